// Round 13
// baseline (355.947 us; speedup 1.0000x reference)
//
#include <hip/hip_runtime.h>
#include <hip/hip_fp16.h>

#define NEG_SLOPE 0.2f
#define NPB 128            // nodes per bucket (dst >> 7); requires N <= 131072
#define MAXB 1024          // max buckets
#define CAPSHIFT 13        // 8192 edges per bucket region (padded layout)
#define CAP (1 << CAPSHIFT)

__device__ __forceinline__ unsigned pk2(float a, float b) {
    __half2 h = __floats2half2_rn(a, b);
    return *(unsigned*)&h;
}
__device__ __forceinline__ float exh(unsigned u, int hi) {
    __half2 h = *(__half2*)&u;
    return hi ? __high2float(h) : __low2float(h);
}

// ===========================================================================
// kA (fused): blocks [0,TB) scatter edges into fixed-capacity bucket regions
// (packed (src<<7)|(dst&127)); blocks [TB, TB+NB) compute row1/ad1 (layer-1
// logits, fold recomputed locally in LDS); block TB also writes global fold.
// ===========================================================================
__global__ void kA(const int* __restrict__ src, const int* __restrict__ dst,
                   const float* __restrict__ x,
                   const float* __restrict__ W1,
                   const float* __restrict__ s1, const float* __restrict__ d1,
                   const float* __restrict__ W2,
                   const float* __restrict__ s2, const float* __restrict__ d2,
                   float* __restrict__ fold,
                   float* __restrict__ row1, float* __restrict__ ad1,
                   int* __restrict__ bcur, int* __restrict__ ebuf,
                   int E, int N, int nbuck, int TB)
{
    int bid = blockIdx.x;
    if (bid < TB) {
        // ---- edge scatter tile ----
        __shared__ int hist[MAXB];
        __shared__ int base[MAXB];
        __shared__ int pk[4096];
        __shared__ unsigned short pb[4096];
        for (int b = threadIdx.x; b < nbuck; b += blockDim.x) hist[b] = 0;
        __syncthreads();
        int tile = bid * 4096;
        int cnt = min(4096, E - tile);
        for (int k = threadIdx.x; k < cnt; k += blockDim.x) {
            int i = tile + k;
            int d = dst[i];
            int b = d >> 7;
            pk[k] = (src[i] << 7) | (d & 127);
            pb[k] = (unsigned short)b;
            atomicAdd(&hist[b], 1);
        }
        __syncthreads();
        for (int b = threadIdx.x; b < nbuck; b += blockDim.x) {
            int v = hist[b];
            base[b] = v ? atomicAdd(&bcur[b], v) : 0;
            hist[b] = 0;                  // reuse as rank cursor
        }
        __syncthreads();
        for (int k = threadIdx.x; k < cnt; k += blockDim.x) {
            int b = pb[k];
            int r = atomicAdd(&hist[b], 1);
            ebuf[((size_t)b << CAPSHIFT) + base[b] + r] = pk[k];
        }
    } else {
        // ---- node tile: layer-1 logits + row1 pack ----
        int nb = bid - TB;
        __shared__ float f1[48];
        int t = threadIdx.x;
        if (t < 48) {
            int isd = t >= 24;
            int u = isd ? t - 24 : t;
            int h = u / 6, k = u % 6;
            const float* av = isd ? d1 : s1;
            float v = 0.f;
            for (int c = 0; c < 6; ++c) v += W1[k * 24 + h * 6 + c] * av[h * 6 + c];
            f1[t] = v;
        }
        if (nb == 0) {      // also publish the full fold table (for gather1)
            if (t < 24) {
                int h = t / 6, k = t % 6;
                float v = 0.f;
                for (int c = 0; c < 6; ++c) v += W1[k * 24 + h * 6 + c] * s1[h * 6 + c];
                fold[t] = v;
            } else if (t < 48) {
                int u = t - 24, h = u / 6, k = u % 6;
                float v = 0.f;
                for (int c = 0; c < 6; ++c) v += W1[k * 24 + h * 6 + c] * d1[h * 6 + c];
                fold[t] = v;
            } else if (t < 144) {
                int u = t - 48, h = u / 24, k = u % 24;
                float v = 0.f;
                for (int c = 0; c < 30; ++c) v += W2[k * 120 + h * 30 + c] * s2[h * 30 + c];
                fold[t] = v;
            } else if (t < 240) {
                int u = t - 144, h = u / 24, k = u % 24;
                float v = 0.f;
                for (int c = 0; c < 30; ++c) v += W2[k * 120 + h * 30 + c] * d2[h * 30 + c];
                fold[t] = v;
            }
        }
        __syncthreads();

        int n = nb * blockDim.x + t;
        if (n >= N) return;
        float xv[6];
#pragma unroll
        for (int k = 0; k < 6; ++k) xv[k] = x[n * 6 + k];
        float as[4];
#pragma unroll
        for (int h = 0; h < 4; ++h) {
            float a = 0.f, d = 0.f;
#pragma unroll
            for (int k = 0; k < 6; ++k) {
                a += xv[k] * f1[h * 6 + k];
                d += xv[k] * f1[24 + h * 6 + k];
            }
            as[h] = a;
            ad1[n * 4 + h] = d;
        }
        uint4 u0, u1;
        u0.x = pk2(as[0], as[1]);
        u0.y = pk2(as[2], as[3]);
        u0.z = __float_as_uint(xv[0]);
        u0.w = __float_as_uint(xv[1]);
        u1.x = __float_as_uint(xv[2]);
        u1.y = __float_as_uint(xv[3]);
        u1.z = __float_as_uint(xv[4]);
        u1.w = __float_as_uint(xv[5]);
        uint4* rp = (uint4*)row1 + (size_t)n * 2;
        rp[0] = u0; rp[1] = u1;
    }
}

// ===========================================================================
// P3: within-bucket counting sort -> exact per-node CSR (padded regions).
// rowp[n] is an ABSOLUTE offset into the padded esrc array.
// ===========================================================================
__global__ void p3_sort(const int* __restrict__ bcur,
                        const int* __restrict__ ebuf,
                        int* __restrict__ rowp, int* __restrict__ deg,
                        int* __restrict__ esrc, int N)
{
    __shared__ int hist[NPB];
    __shared__ int ls[NPB];
    int b = blockIdx.x;
    int n0 = b * NPB;
    if (threadIdx.x < NPB) hist[threadIdx.x] = 0;
    __syncthreads();
    size_t es = (size_t)b << CAPSHIFT;
    int ec = min(bcur[b], CAP);
    for (int k = threadIdx.x; k < ec; k += blockDim.x)
        atomicAdd(&hist[ebuf[es + k] & 127], 1);
    __syncthreads();
    if (threadIdx.x < NPB) ls[threadIdx.x] = hist[threadIdx.x];
    __syncthreads();
    for (int off = 1; off < NPB; off <<= 1) {
        int v = 0;
        if (threadIdx.x < NPB && threadIdx.x >= off) v = ls[threadIdx.x - off];
        __syncthreads();
        if (threadIdx.x < NPB) ls[threadIdx.x] += v;
        __syncthreads();
    }
    if (threadIdx.x < NPB) {
        int ex = ls[threadIdx.x] - hist[threadIdx.x];   // exclusive
        ls[threadIdx.x] = ex;
        int n = n0 + threadIdx.x;
        if (n < N) { rowp[n] = (int)es + ex; deg[n] = hist[threadIdx.x]; }
        hist[threadIdx.x] = 0;            // reuse as cursor
    }
    __syncthreads();
    for (int k = threadIdx.x; k < ec; k += blockDim.x) {
        int v = ebuf[es + k];
        int ln = v & 127;
        int r = atomicAdd(&hist[ln], 1);
        esrc[es + ls[ln] + r] = v >> 7;
    }
}

// ===========================================================================
// Gather layer 1 (8 threads/node: h=o&3, half=o>>2). Contiguous half edge
// ranges; DEPTH-2 software pipeline: next row's loads are issued before the
// current row is consumed (named scalars, no arrays -> stays in VGPRs).
// Epilogue: project W1_h, fused layer-2 logits, write
// row2[n] = [as2 4xfp16 | g 24xfp16] (64B) + ad2.
// ===========================================================================
__global__ void __launch_bounds__(256, 4)
k_gather1(const int* __restrict__ rowp, const int* __restrict__ deg,
          const int* __restrict__ esrc,
          const float* __restrict__ row1,
          const float* __restrict__ ad1,
          const float* __restrict__ W1, const float* __restrict__ b1,
          const float* __restrict__ fold,
          float* __restrict__ row2,
          float* __restrict__ ad2, int N)
{
    int t = blockIdx.x * blockDim.x + threadIdx.x;
    int n = t >> 3;
    if (n >= N) return;
    int o = t & 7;
    int h = o & 3;
    int half = o >> 2;
    float adn = ad1[n * 4 + h];
    const uint4* R = (const uint4*)row1;

    float acc[6] = {0.f, 0.f, 0.f, 0.f, 0.f, 0.f};
    float den = 0.f;

#define G1_EDGE(A, B)                                                         \
    {                                                                         \
        float as = exh((h < 2) ? (A).x : (A).y, h & 1);                       \
        float e = as + adn; e = e > 0.f ? e : NEG_SLOPE * e;                  \
        float w = expf(e);                                                    \
        den += w;                                                             \
        acc[0] += w * __uint_as_float((A).z);                                 \
        acc[1] += w * __uint_as_float((A).w);                                 \
        acc[2] += w * __uint_as_float((B).x);                                 \
        acc[3] += w * __uint_as_float((B).y);                                 \
        acc[4] += w * __uint_as_float((B).z);                                 \
        acc[5] += w * __uint_as_float((B).w);                                 \
    }

    if (half == 0) {   // self loop
        uint4 u0 = R[(size_t)n * 2], u1 = R[(size_t)n * 2 + 1];
        G1_EDGE(u0, u1)
    }
    int start = rowp[n], cnt = deg[n];
    int c0 = (cnt + 1) >> 1;
    int lo = start + (half ? c0 : 0);
    int hi = start + (half ? cnt : c0);
    if (lo < hi) {
        int scur = esrc[lo];
        int snxt = esrc[lo + 1];          // padded-safe (index read only)
        uint4 A = R[(size_t)scur * 2], B = R[(size_t)scur * 2 + 1];
        for (int k = lo + 1; k < hi; ++k) {
            uint4 An = R[(size_t)snxt * 2], Bn = R[(size_t)snxt * 2 + 1];
            int snn = esrc[k + 1];        // padded-safe
            G1_EDGE(A, B)
            A = An; B = Bn; snxt = snn;
        }
        G1_EDGE(A, B)
    }
#undef G1_EDGE
    // merge halves
    den += __shfl_xor(den, 4);
#pragma unroll
    for (int j = 0; j < 6; ++j) acc[j] += __shfl_xor(acc[j], 4);

    float inv = 1.f / (den + 1e-16f);
    float m[6];
#pragma unroll
    for (int j = 0; j < 6; ++j) m[j] = acc[j] * inv;

    // project W1_h: gc[c] = relu(m . W1[:, h*6+c] + b1)
    float gc[6];
#pragma unroll
    for (int c = 0; c < 6; ++c) {
        float v = b1[h * 6 + c];
#pragma unroll
        for (int j = 0; j < 6; ++j) v += m[j] * W1[j * 24 + h * 6 + c];
        gc[c] = v > 0.f ? v : 0.f;
    }
    // fused layer-2 logits (partial over this lane's 6 channels, all 4 heads)
    float pas[4], pad[4];
#pragma unroll
    for (int hh = 0; hh < 4; ++hh) {
        float a = 0.f, d = 0.f;
#pragma unroll
        for (int c = 0; c < 6; ++c) {
            a += gc[c] * fold[48 + hh * 24 + h * 6 + c];
            d += gc[c] * fold[144 + hh * 24 + h * 6 + c];
        }
        pas[hh] = a; pad[hh] = d;
    }
#pragma unroll
    for (int hh = 0; hh < 4; ++hh) {
        pas[hh] += __shfl_xor(pas[hh], 1);
        pas[hh] += __shfl_xor(pas[hh], 2);
        pad[hh] += __shfl_xor(pad[hh], 1);
        pad[hh] += __shfl_xor(pad[hh], 2);
    }
    if (half == 0) {
        unsigned* rp = (unsigned*)row2 + (size_t)n * 16;
        if (h == 0) {
            rp[0] = pk2(pas[0], pas[1]);
            rp[1] = pk2(pas[2], pas[3]);
        }
        rp[2 + 3 * h + 0] = pk2(gc[0], gc[1]);
        rp[2 + 3 * h + 1] = pk2(gc[2], gc[3]);
        rp[2 + 3 * h + 2] = pk2(gc[4], gc[5]);
        ad2[n * 4 + h] = pad[h];
    }
}

// ===========================================================================
// Gather layer 2, single pass: 64B row2 = [as2 4xfp16 | g 24xfp16 | pad].
// 8 threads/node, contiguous halves, DEPTH-2 software pipeline (named
// scalars A..D / An..Dn), W2 read from global (L2 broadcast). Epilogue:
// project 15 ch/half, quad shfl head-sum, o==0 runs mean + b2 + relu + MLP.
// ===========================================================================
__global__ void __launch_bounds__(256, 4)
k_gather2(const int* __restrict__ rowp, const int* __restrict__ deg,
          const int* __restrict__ esrc,
          const float* __restrict__ row2,
          const float* __restrict__ ad2,
          const float* __restrict__ W2, const float* __restrict__ b2,
          const float* __restrict__ fw1, const float* __restrict__ fb1,
          const float* __restrict__ fw2, const float* __restrict__ fb2,
          float* __restrict__ out, int N)
{
    int t = blockIdx.x * blockDim.x + threadIdx.x;
    int n = t >> 3;
    if (n >= N) return;
    int o = t & 7;
    int h = o & 3;
    int half = o >> 2;
    float adn = ad2[n * 4 + h];
    const uint4* R = (const uint4*)row2;     // 4 uint4 per row (last half-used)
    const uint2* R2 = (const uint2*)row2;    // uint2 index: n*8 + 6 -> g20..g23

    float acc[24];
#pragma unroll
    for (int j = 0; j < 24; ++j) acc[j] = 0.f;
    float den = 0.f;

#define G2_EDGE(A, B, C, D)                                                   \
    {                                                                         \
        float as = exh((h < 2) ? (A).x : (A).y, h & 1);                       \
        float e = as + adn; e = e > 0.f ? e : NEG_SLOPE * e;                  \
        float w = expf(e);                                                    \
        den += w;                                                             \
        float2 g0 = __half22float2(*(__half2*)&(A).z);                        \
        float2 g1 = __half22float2(*(__half2*)&(A).w);                        \
        float2 g2 = __half22float2(*(__half2*)&(B).x);                        \
        float2 g3 = __half22float2(*(__half2*)&(B).y);                        \
        float2 g4 = __half22float2(*(__half2*)&(B).z);                        \
        float2 g5 = __half22float2(*(__half2*)&(B).w);                        \
        float2 g6 = __half22float2(*(__half2*)&(C).x);                        \
        float2 g7 = __half22float2(*(__half2*)&(C).y);                        \
        float2 g8 = __half22float2(*(__half2*)&(C).z);                        \
        float2 g9 = __half22float2(*(__half2*)&(C).w);                        \
        float2 gA = __half22float2(*(__half2*)&(D).x);                        \
        float2 gB = __half22float2(*(__half2*)&(D).y);                        \
        acc[0] += w * g0.x;  acc[1] += w * g0.y;                              \
        acc[2] += w * g1.x;  acc[3] += w * g1.y;                              \
        acc[4] += w * g2.x;  acc[5] += w * g2.y;                              \
        acc[6] += w * g3.x;  acc[7] += w * g3.y;                              \
        acc[8] += w * g4.x;  acc[9] += w * g4.y;                              \
        acc[10] += w * g5.x; acc[11] += w * g5.y;                             \
        acc[12] += w * g6.x; acc[13] += w * g6.y;                             \
        acc[14] += w * g7.x; acc[15] += w * g7.y;                             \
        acc[16] += w * g8.x; acc[17] += w * g8.y;                             \
        acc[18] += w * g9.x; acc[19] += w * g9.y;                             \
        acc[20] += w * gA.x; acc[21] += w * gA.y;                             \
        acc[22] += w * gB.x; acc[23] += w * gB.y;                             \
    }

    if (half == 0) {   // self loop
        uint4 A = R[(size_t)n * 4], B = R[(size_t)n * 4 + 1],
              C = R[(size_t)n * 4 + 2];
        uint2 D = R2[(size_t)n * 8 + 6];
        G2_EDGE(A, B, C, D)
    }
    int start = rowp[n], cnt = deg[n];
    int c0 = (cnt + 1) >> 1;
    int lo = start + (half ? c0 : 0);
    int hi = start + (half ? cnt : c0);
    if (lo < hi) {
        int scur = esrc[lo];
        int snxt = esrc[lo + 1];          // padded-safe (index read only)
        uint4 A = R[(size_t)scur * 4], B = R[(size_t)scur * 4 + 1],
              C = R[(size_t)scur * 4 + 2];
        uint2 D = R2[(size_t)scur * 8 + 6];
        for (int k = lo + 1; k < hi; ++k) {
            uint4 An = R[(size_t)snxt * 4], Bn = R[(size_t)snxt * 4 + 1],
                  Cn = R[(size_t)snxt * 4 + 2];
            uint2 Dn = R2[(size_t)snxt * 8 + 6];
            int snn = esrc[k + 1];        // padded-safe
            G2_EDGE(A, B, C, D)
            A = An; B = Bn; C = Cn; D = Dn; snxt = snn;
        }
        G2_EDGE(A, B, C, D)
    }
#undef G2_EDGE

    // merge halves
    den += __shfl_xor(den, 4);
#pragma unroll
    for (int j = 0; j < 24; ++j) acc[j] += __shfl_xor(acc[j], 4);
    float inv = 1.f / (den + 1e-16f);
#pragma unroll
    for (int j = 0; j < 24; ++j) acc[j] *= inv;

    // project 15 channels per half: c = half*15 + cc (W2 from global/L2)
    float zz[15];
#pragma unroll
    for (int cc = 0; cc < 15; ++cc) {
        int c = half * 15 + cc;
        float v = 0.f;
#pragma unroll
        for (int j = 0; j < 24; ++j) v += acc[j] * W2[j * 120 + h * 30 + c];
        v += __shfl_xor(v, 1);
        v += __shfl_xor(v, 2);
        zz[cc] = v;          // head-summed; half0: ch 0-14, half1: ch 15-29
    }
    float zhi[15];
#pragma unroll
    for (int cc = 0; cc < 15; ++cc) zhi[cc] = __shfl_xor(zz[cc], 4);

    if (o == 0) {
        float z[30];
#pragma unroll
        for (int cc = 0; cc < 15; ++cc) {
            float v0 = 0.25f * zz[cc] + b2[cc];
            float v1 = 0.25f * zhi[cc] + b2[15 + cc];
            z[cc]      = v0 > 0.f ? v0 : 0.f;
            z[15 + cc] = v1 > 0.f ? v1 : 0.f;
        }
        float m2[15];
#pragma unroll
        for (int j = 0; j < 15; ++j) {
            float v = fb1[j];
#pragma unroll
            for (int c = 0; c < 30; ++c) v += z[c] * fw1[c * 15 + j];
            m2[j] = v > 0.f ? v : 0.f;
        }
#pragma unroll
        for (int j = 0; j < 2; ++j) {
            float v = fb2[j];
#pragma unroll
            for (int c = 0; c < 15; ++c) v += m2[c] * fw2[c * 2 + j];
            out[(size_t)n * 2 + j] = v;
        }
    }
}

// ===========================================================================
extern "C" void kernel_launch(void* const* d_in, const int* in_sizes, int n_in,
                              void* d_out, int out_size, void* d_ws, size_t ws_size,
                              hipStream_t stream)
{
    const float* x    = (const float*)d_in[0];
    const int*   ei   = (const int*)  d_in[1];
    // d_in[2] = edge_attr (ignored)
    const float* w1   = (const float*)d_in[3];
    const float* as1w = (const float*)d_in[4];
    const float* ad1w = (const float*)d_in[5];
    const float* b1   = (const float*)d_in[6];
    const float* w2   = (const float*)d_in[7];
    const float* as2w = (const float*)d_in[8];
    const float* ad2w = (const float*)d_in[9];
    const float* b2   = (const float*)d_in[10];
    const float* fw1  = (const float*)d_in[11];
    const float* fb1  = (const float*)d_in[12];
    const float* fw2  = (const float*)d_in[13];
    const float* fb2  = (const float*)d_in[14];

    const int N = in_sizes[0] / 6;
    const int E = in_sizes[1] / 2;
    const int* src = ei;
    const int* dst = ei + E;
    const int nbuck = (N + NPB - 1) / NPB;     // <= 1024 for N <= 131072

    float* ws = (float*)d_ws;
    size_t off = 0;
    float* row1 = ws + off; off += (size_t)N * 8;    // 32B rows
    float* row2 = ws + off; off += (size_t)N * 16;   // 64B rows
    float* ad1  = ws + off; off += (size_t)N * 4;
    float* ad2  = ws + off; off += (size_t)N * 4;
    float* fold = ws + off; off += 256;

    int* iw = (int*)(ws + off);
    size_t ioff = 0;
    int* bcur = iw + ioff; ioff += MAXB;               // zeroed each call
    int* rowp = iw + ioff; ioff += N;
    int* deg  = iw + ioff; ioff += N;
    int* ebuf = iw + ioff; ioff += ((size_t)nbuck << CAPSHIFT) + 64;
    int* esrc = iw + ioff; ioff += ((size_t)nbuck << CAPSHIFT) + 64;
    // total ~65 MB of d_ws

    hipMemsetAsync(bcur, 0, MAXB * sizeof(int), stream);

    const int B = 256;
    const int NB = (N + B - 1) / B;
    const int TB = (E + 4095) / 4096;
    const int OB = (int)(((size_t)N * 8 + B - 1) / B);

    // fused: edge scatter + fold + layer-1 logits/row pack
    kA       <<<TB + NB, B, 0, stream>>>(src, dst, x, w1, as1w, ad1w,
                                         w2, as2w, ad2w, fold, row1, ad1,
                                         bcur, ebuf, E, N, nbuck, TB);
    // within-bucket counting sort -> per-node CSR (padded regions)
    p3_sort  <<<nbuck, B, 0, stream>>>(bcur, ebuf, rowp, deg, esrc, N);

    // layer 1 gather (+ fused layer-2 logits)
    k_gather1<<<OB, B, 0, stream>>>(rowp, deg, esrc, row1, ad1, w1, b1, fold,
                                    row2, ad2, N);

    // layer 2 gather (+ fused head-mean + MLP)
    k_gather2<<<OB, B, 0, stream>>>(rowp, deg, esrc, row2, ad2, w2, b2,
                                    fw1, fb1, fw2, fb2, (float*)d_out, N);
}

// Round 14
// 327.173 us; speedup vs baseline: 1.0879x; 1.0879x over previous
//
#include <hip/hip_runtime.h>
#include <hip/hip_fp16.h>

#define NEG_SLOPE 0.2f
#define NPB 128            // nodes per bucket (dst >> 7); requires N <= 131072
#define MAXB 1024          // max buckets
#define CAPSHIFT 13        // 8192 edges per bucket region (padded layout)
#define CAP (1 << CAPSHIFT)

__device__ __forceinline__ unsigned pk2(float a, float b) {
    __half2 h = __floats2half2_rn(a, b);
    return *(unsigned*)&h;
}
__device__ __forceinline__ float exh(unsigned u, int hi) {
    __half2 h = *(__half2*)&u;
    return hi ? __high2float(h) : __low2float(h);
}

// ===========================================================================
// kA (fused): blocks [0,TB) scatter edges into fixed-capacity bucket regions
// (packed (src<<7)|(dst&127)); blocks [TB, TB+NB) compute row1/ad1 (layer-1
// logits, fold recomputed locally in LDS); block TB also writes global fold.
// ===========================================================================
__global__ void kA(const int* __restrict__ src, const int* __restrict__ dst,
                   const float* __restrict__ x,
                   const float* __restrict__ W1,
                   const float* __restrict__ s1, const float* __restrict__ d1,
                   const float* __restrict__ W2,
                   const float* __restrict__ s2, const float* __restrict__ d2,
                   float* __restrict__ fold,
                   float* __restrict__ row1, float* __restrict__ ad1,
                   int* __restrict__ bcur, int* __restrict__ ebuf,
                   int E, int N, int nbuck, int TB)
{
    int bid = blockIdx.x;
    if (bid < TB) {
        // ---- edge scatter tile ----
        __shared__ int hist[MAXB];
        __shared__ int base[MAXB];
        __shared__ int pk[4096];
        __shared__ unsigned short pb[4096];
        for (int b = threadIdx.x; b < nbuck; b += blockDim.x) hist[b] = 0;
        __syncthreads();
        int tile = bid * 4096;
        int cnt = min(4096, E - tile);
        for (int k = threadIdx.x; k < cnt; k += blockDim.x) {
            int i = tile + k;
            int d = dst[i];
            int b = d >> 7;
            pk[k] = (src[i] << 7) | (d & 127);
            pb[k] = (unsigned short)b;
            atomicAdd(&hist[b], 1);
        }
        __syncthreads();
        for (int b = threadIdx.x; b < nbuck; b += blockDim.x) {
            int v = hist[b];
            base[b] = v ? atomicAdd(&bcur[b], v) : 0;
            hist[b] = 0;                  // reuse as rank cursor
        }
        __syncthreads();
        for (int k = threadIdx.x; k < cnt; k += blockDim.x) {
            int b = pb[k];
            int r = atomicAdd(&hist[b], 1);
            ebuf[((size_t)b << CAPSHIFT) + base[b] + r] = pk[k];
        }
    } else {
        // ---- node tile: layer-1 logits + row1 pack ----
        int nb = bid - TB;
        __shared__ float f1[48];
        int t = threadIdx.x;
        if (t < 48) {
            int isd = t >= 24;
            int u = isd ? t - 24 : t;
            int h = u / 6, k = u % 6;
            const float* av = isd ? d1 : s1;
            float v = 0.f;
            for (int c = 0; c < 6; ++c) v += W1[k * 24 + h * 6 + c] * av[h * 6 + c];
            f1[t] = v;
        }
        if (nb == 0) {      // also publish the full fold table (for gather1)
            if (t < 24) {
                int h = t / 6, k = t % 6;
                float v = 0.f;
                for (int c = 0; c < 6; ++c) v += W1[k * 24 + h * 6 + c] * s1[h * 6 + c];
                fold[t] = v;
            } else if (t < 48) {
                int u = t - 24, h = u / 6, k = u % 6;
                float v = 0.f;
                for (int c = 0; c < 6; ++c) v += W1[k * 24 + h * 6 + c] * d1[h * 6 + c];
                fold[t] = v;
            } else if (t < 144) {
                int u = t - 48, h = u / 24, k = u % 24;
                float v = 0.f;
                for (int c = 0; c < 30; ++c) v += W2[k * 120 + h * 30 + c] * s2[h * 30 + c];
                fold[t] = v;
            } else if (t < 240) {
                int u = t - 144, h = u / 24, k = u % 24;
                float v = 0.f;
                for (int c = 0; c < 30; ++c) v += W2[k * 120 + h * 30 + c] * d2[h * 30 + c];
                fold[t] = v;
            }
        }
        __syncthreads();

        int n = nb * blockDim.x + t;
        if (n >= N) return;
        float xv[6];
#pragma unroll
        for (int k = 0; k < 6; ++k) xv[k] = x[n * 6 + k];
        float as[4];
#pragma unroll
        for (int h = 0; h < 4; ++h) {
            float a = 0.f, d = 0.f;
#pragma unroll
            for (int k = 0; k < 6; ++k) {
                a += xv[k] * f1[h * 6 + k];
                d += xv[k] * f1[24 + h * 6 + k];
            }
            as[h] = a;
            ad1[n * 4 + h] = d;
        }
        uint4 u0, u1;
        u0.x = pk2(as[0], as[1]);
        u0.y = pk2(as[2], as[3]);
        u0.z = __float_as_uint(xv[0]);
        u0.w = __float_as_uint(xv[1]);
        u1.x = __float_as_uint(xv[2]);
        u1.y = __float_as_uint(xv[3]);
        u1.z = __float_as_uint(xv[4]);
        u1.w = __float_as_uint(xv[5]);
        uint4* rp = (uint4*)row1 + (size_t)n * 2;
        rp[0] = u0; rp[1] = u1;
    }
}

// ===========================================================================
// P3: within-bucket counting sort -> exact per-node CSR (padded regions).
// rowp[n] is an ABSOLUTE offset into the padded esrc array.
// ===========================================================================
__global__ void p3_sort(const int* __restrict__ bcur,
                        const int* __restrict__ ebuf,
                        int* __restrict__ rowp, int* __restrict__ deg,
                        int* __restrict__ esrc, int N)
{
    __shared__ int hist[NPB];
    __shared__ int ls[NPB];
    int b = blockIdx.x;
    int n0 = b * NPB;
    if (threadIdx.x < NPB) hist[threadIdx.x] = 0;
    __syncthreads();
    size_t es = (size_t)b << CAPSHIFT;
    int ec = min(bcur[b], CAP);
    for (int k = threadIdx.x; k < ec; k += blockDim.x)
        atomicAdd(&hist[ebuf[es + k] & 127], 1);
    __syncthreads();
    if (threadIdx.x < NPB) ls[threadIdx.x] = hist[threadIdx.x];
    __syncthreads();
    for (int off = 1; off < NPB; off <<= 1) {
        int v = 0;
        if (threadIdx.x < NPB && threadIdx.x >= off) v = ls[threadIdx.x - off];
        __syncthreads();
        if (threadIdx.x < NPB) ls[threadIdx.x] += v;
        __syncthreads();
    }
    if (threadIdx.x < NPB) {
        int ex = ls[threadIdx.x] - hist[threadIdx.x];   // exclusive
        ls[threadIdx.x] = ex;
        int n = n0 + threadIdx.x;
        if (n < N) { rowp[n] = (int)es + ex; deg[n] = hist[threadIdx.x]; }
        hist[threadIdx.x] = 0;            // reuse as cursor
    }
    __syncthreads();
    for (int k = threadIdx.x; k < ec; k += blockDim.x) {
        int v = ebuf[es + k];
        int ln = v & 127;
        int r = atomicAdd(&hist[ln], 1);
        esrc[es + ls[ln] + r] = v >> 7;
    }
}

// ===========================================================================
// Gather layer 1 (8 threads/node: h=o&3, half=o>>2). Contiguous half edge
// ranges, esrc index prefetched one iteration ahead (padded array makes the
// k+1 read always in-bounds). Epilogue: project W1_h, fused layer-2 logits,
// write row2[n] = [as2 4xfp16 | g 24xfp16] (64B) + ad2.
// ===========================================================================
__global__ void __launch_bounds__(256, 4)
k_gather1(const int* __restrict__ rowp, const int* __restrict__ deg,
          const int* __restrict__ esrc,
          const float* __restrict__ row1,
          const float* __restrict__ ad1,
          const float* __restrict__ W1, const float* __restrict__ b1,
          const float* __restrict__ fold,
          float* __restrict__ row2,
          float* __restrict__ ad2, int N)
{
    int t = blockIdx.x * blockDim.x + threadIdx.x;
    int n = t >> 3;
    if (n >= N) return;
    int o = t & 7;
    int h = o & 3;
    int half = o >> 2;
    float adn = ad1[n * 4 + h];
    const uint4* R = (const uint4*)row1;

    float acc[6] = {0.f, 0.f, 0.f, 0.f, 0.f, 0.f};
    float den = 0.f;

#define G1_EDGE(A, B)                                                         \
    {                                                                         \
        float as = exh((h < 2) ? (A).x : (A).y, h & 1);                       \
        float e = as + adn; e = e > 0.f ? e : NEG_SLOPE * e;                  \
        float w = expf(e);                                                    \
        den += w;                                                             \
        acc[0] += w * __uint_as_float((A).z);                                 \
        acc[1] += w * __uint_as_float((A).w);                                 \
        acc[2] += w * __uint_as_float((B).x);                                 \
        acc[3] += w * __uint_as_float((B).y);                                 \
        acc[4] += w * __uint_as_float((B).z);                                 \
        acc[5] += w * __uint_as_float((B).w);                                 \
    }

    if (half == 0) {   // self loop
        uint4 u0 = R[(size_t)n * 2], u1 = R[(size_t)n * 2 + 1];
        G1_EDGE(u0, u1)
    }
    int start = rowp[n], cnt = deg[n];
    int c0 = (cnt + 1) >> 1;
    int lo = start + (half ? c0 : 0);
    int hi = start + (half ? cnt : c0);
    int snext = esrc[lo];                 // padded-safe
    for (int k = lo; k < hi; ++k) {
        int s = snext;
        snext = esrc[k + 1];              // padded-safe prefetch
        uint4 u0 = R[(size_t)s * 2], u1 = R[(size_t)s * 2 + 1];
        G1_EDGE(u0, u1)
    }
#undef G1_EDGE
    // merge halves
    den += __shfl_xor(den, 4);
#pragma unroll
    for (int j = 0; j < 6; ++j) acc[j] += __shfl_xor(acc[j], 4);

    float inv = 1.f / (den + 1e-16f);
    float m[6];
#pragma unroll
    for (int j = 0; j < 6; ++j) m[j] = acc[j] * inv;

    // project W1_h: gc[c] = relu(m . W1[:, h*6+c] + b1)
    float gc[6];
#pragma unroll
    for (int c = 0; c < 6; ++c) {
        float v = b1[h * 6 + c];
#pragma unroll
        for (int j = 0; j < 6; ++j) v += m[j] * W1[j * 24 + h * 6 + c];
        gc[c] = v > 0.f ? v : 0.f;
    }
    // fused layer-2 logits (partial over this lane's 6 channels, all 4 heads)
    float pas[4], pad[4];
#pragma unroll
    for (int hh = 0; hh < 4; ++hh) {
        float a = 0.f, d = 0.f;
#pragma unroll
        for (int c = 0; c < 6; ++c) {
            a += gc[c] * fold[48 + hh * 24 + h * 6 + c];
            d += gc[c] * fold[144 + hh * 24 + h * 6 + c];
        }
        pas[hh] = a; pad[hh] = d;
    }
#pragma unroll
    for (int hh = 0; hh < 4; ++hh) {
        pas[hh] += __shfl_xor(pas[hh], 1);
        pas[hh] += __shfl_xor(pas[hh], 2);
        pad[hh] += __shfl_xor(pad[hh], 1);
        pad[hh] += __shfl_xor(pad[hh], 2);
    }
    if (half == 0) {
        unsigned* rp = (unsigned*)row2 + (size_t)n * 16;
        if (h == 0) {
            rp[0] = pk2(pas[0], pas[1]);
            rp[1] = pk2(pas[2], pas[3]);
        }
        rp[2 + 3 * h + 0] = pk2(gc[0], gc[1]);
        rp[2 + 3 * h + 1] = pk2(gc[2], gc[3]);
        rp[2 + 3 * h + 2] = pk2(gc[4], gc[5]);
        ad2[n * 4 + h] = pad[h];
    }
}

// ===========================================================================
// Gather layer 2, single pass: 64B row2 = [as2 4xfp16 | g 24xfp16 | pad].
// 8 threads/node, contiguous halves, esrc prefetch, W2 from global (L2
// broadcast). Epilogue: project 15 ch/half, quad shfl head-sum, o==0 runs
// mean + b2 + relu + MLP 30->15->2.
// ===========================================================================
__global__ void __launch_bounds__(256, 4)
k_gather2(const int* __restrict__ rowp, const int* __restrict__ deg,
          const int* __restrict__ esrc,
          const float* __restrict__ row2,
          const float* __restrict__ ad2,
          const float* __restrict__ W2, const float* __restrict__ b2,
          const float* __restrict__ fw1, const float* __restrict__ fb1,
          const float* __restrict__ fw2, const float* __restrict__ fb2,
          float* __restrict__ out, int N)
{
    int t = blockIdx.x * blockDim.x + threadIdx.x;
    int n = t >> 3;
    if (n >= N) return;
    int o = t & 7;
    int h = o & 3;
    int half = o >> 2;
    float adn = ad2[n * 4 + h];
    const uint4* R = (const uint4*)row2;     // 4 uint4 per row (last half-used)
    const uint2* R2 = (const uint2*)row2;    // uint2 index: n*8 + 6 -> g20..g23

    float acc[24];
#pragma unroll
    for (int j = 0; j < 24; ++j) acc[j] = 0.f;
    float den = 0.f;

#define G2_EDGE(A, B, C, D)                                                   \
    {                                                                         \
        float as = exh((h < 2) ? (A).x : (A).y, h & 1);                       \
        float e = as + adn; e = e > 0.f ? e : NEG_SLOPE * e;                  \
        float w = expf(e);                                                    \
        den += w;                                                             \
        float2 g0 = __half22float2(*(__half2*)&(A).z);                        \
        float2 g1 = __half22float2(*(__half2*)&(A).w);                        \
        float2 g2 = __half22float2(*(__half2*)&(B).x);                        \
        float2 g3 = __half22float2(*(__half2*)&(B).y);                        \
        float2 g4 = __half22float2(*(__half2*)&(B).z);                        \
        float2 g5 = __half22float2(*(__half2*)&(B).w);                        \
        float2 g6 = __half22float2(*(__half2*)&(C).x);                        \
        float2 g7 = __half22float2(*(__half2*)&(C).y);                        \
        float2 g8 = __half22float2(*(__half2*)&(C).z);                        \
        float2 g9 = __half22float2(*(__half2*)&(C).w);                        \
        float2 gA = __half22float2(*(__half2*)&(D).x);                        \
        float2 gB = __half22float2(*(__half2*)&(D).y);                        \
        acc[0] += w * g0.x;  acc[1] += w * g0.y;                              \
        acc[2] += w * g1.x;  acc[3] += w * g1.y;                              \
        acc[4] += w * g2.x;  acc[5] += w * g2.y;                              \
        acc[6] += w * g3.x;  acc[7] += w * g3.y;                              \
        acc[8] += w * g4.x;  acc[9] += w * g4.y;                              \
        acc[10] += w * g5.x; acc[11] += w * g5.y;                             \
        acc[12] += w * g6.x; acc[13] += w * g6.y;                             \
        acc[14] += w * g7.x; acc[15] += w * g7.y;                             \
        acc[16] += w * g8.x; acc[17] += w * g8.y;                             \
        acc[18] += w * g9.x; acc[19] += w * g9.y;                             \
        acc[20] += w * gA.x; acc[21] += w * gA.y;                             \
        acc[22] += w * gB.x; acc[23] += w * gB.y;                             \
    }

    if (half == 0) {   // self loop
        uint4 A = R[(size_t)n * 4], B = R[(size_t)n * 4 + 1],
              C = R[(size_t)n * 4 + 2];
        uint2 D = R2[(size_t)n * 8 + 6];
        G2_EDGE(A, B, C, D)
    }
    int start = rowp[n], cnt = deg[n];
    int c0 = (cnt + 1) >> 1;
    int lo = start + (half ? c0 : 0);
    int hi = start + (half ? cnt : c0);
    int snext = esrc[lo];                 // padded-safe
    for (int k = lo; k < hi; ++k) {
        int s = snext;
        snext = esrc[k + 1];              // padded-safe prefetch
        uint4 A = R[(size_t)s * 4], B = R[(size_t)s * 4 + 1],
              C = R[(size_t)s * 4 + 2];
        uint2 D = R2[(size_t)s * 8 + 6];
        G2_EDGE(A, B, C, D)
    }
#undef G2_EDGE

    // merge halves
    den += __shfl_xor(den, 4);
#pragma unroll
    for (int j = 0; j < 24; ++j) acc[j] += __shfl_xor(acc[j], 4);
    float inv = 1.f / (den + 1e-16f);
#pragma unroll
    for (int j = 0; j < 24; ++j) acc[j] *= inv;

    // project 15 channels per half: c = half*15 + cc (W2 from global/L2)
    float zz[15];
#pragma unroll
    for (int cc = 0; cc < 15; ++cc) {
        int c = half * 15 + cc;
        float v = 0.f;
#pragma unroll
        for (int j = 0; j < 24; ++j) v += acc[j] * W2[j * 120 + h * 30 + c];
        v += __shfl_xor(v, 1);
        v += __shfl_xor(v, 2);
        zz[cc] = v;          // head-summed; half0: ch 0-14, half1: ch 15-29
    }
    float zhi[15];
#pragma unroll
    for (int cc = 0; cc < 15; ++cc) zhi[cc] = __shfl_xor(zz[cc], 4);

    if (o == 0) {
        float z[30];
#pragma unroll
        for (int cc = 0; cc < 15; ++cc) {
            float v0 = 0.25f * zz[cc] + b2[cc];
            float v1 = 0.25f * zhi[cc] + b2[15 + cc];
            z[cc]      = v0 > 0.f ? v0 : 0.f;
            z[15 + cc] = v1 > 0.f ? v1 : 0.f;
        }
        float m2[15];
#pragma unroll
        for (int j = 0; j < 15; ++j) {
            float v = fb1[j];
#pragma unroll
            for (int c = 0; c < 30; ++c) v += z[c] * fw1[c * 15 + j];
            m2[j] = v > 0.f ? v : 0.f;
        }
#pragma unroll
        for (int j = 0; j < 2; ++j) {
            float v = fb2[j];
#pragma unroll
            for (int c = 0; c < 15; ++c) v += m2[c] * fw2[c * 2 + j];
            out[(size_t)n * 2 + j] = v;
        }
    }
}

// ===========================================================================
extern "C" void kernel_launch(void* const* d_in, const int* in_sizes, int n_in,
                              void* d_out, int out_size, void* d_ws, size_t ws_size,
                              hipStream_t stream)
{
    const float* x    = (const float*)d_in[0];
    const int*   ei   = (const int*)  d_in[1];
    // d_in[2] = edge_attr (ignored)
    const float* w1   = (const float*)d_in[3];
    const float* as1w = (const float*)d_in[4];
    const float* ad1w = (const float*)d_in[5];
    const float* b1   = (const float*)d_in[6];
    const float* w2   = (const float*)d_in[7];
    const float* as2w = (const float*)d_in[8];
    const float* ad2w = (const float*)d_in[9];
    const float* b2   = (const float*)d_in[10];
    const float* fw1  = (const float*)d_in[11];
    const float* fb1  = (const float*)d_in[12];
    const float* fw2  = (const float*)d_in[13];
    const float* fb2  = (const float*)d_in[14];

    const int N = in_sizes[0] / 6;
    const int E = in_sizes[1] / 2;
    const int* src = ei;
    const int* dst = ei + E;
    const int nbuck = (N + NPB - 1) / NPB;     // <= 1024 for N <= 131072

    float* ws = (float*)d_ws;
    size_t off = 0;
    float* row1 = ws + off; off += (size_t)N * 8;    // 32B rows
    float* row2 = ws + off; off += (size_t)N * 16;   // 64B rows
    float* ad1  = ws + off; off += (size_t)N * 4;
    float* ad2  = ws + off; off += (size_t)N * 4;
    float* fold = ws + off; off += 256;

    int* iw = (int*)(ws + off);
    size_t ioff = 0;
    int* bcur = iw + ioff; ioff += MAXB;               // zeroed each call
    int* rowp = iw + ioff; ioff += N;
    int* deg  = iw + ioff; ioff += N;
    int* ebuf = iw + ioff; ioff += ((size_t)nbuck << CAPSHIFT) + 64;
    int* esrc = iw + ioff; ioff += ((size_t)nbuck << CAPSHIFT) + 64;
    // total ~65 MB of d_ws

    hipMemsetAsync(bcur, 0, MAXB * sizeof(int), stream);

    const int B = 256;
    const int NB = (N + B - 1) / B;
    const int TB = (E + 4095) / 4096;
    const int OB = (int)(((size_t)N * 8 + B - 1) / B);

    // fused: edge scatter + fold + layer-1 logits/row pack
    kA       <<<TB + NB, B, 0, stream>>>(src, dst, x, w1, as1w, ad1w,
                                         w2, as2w, ad2w, fold, row1, ad1,
                                         bcur, ebuf, E, N, nbuck, TB);
    // within-bucket counting sort -> per-node CSR (padded regions)
    p3_sort  <<<nbuck, B, 0, stream>>>(bcur, ebuf, rowp, deg, esrc, N);

    // layer 1 gather (+ fused layer-2 logits)
    k_gather1<<<OB, B, 0, stream>>>(rowp, deg, esrc, row1, ad1, w1, b1, fold,
                                    row2, ad2, N);

    // layer 2 gather (+ fused head-mean + MLP)
    k_gather2<<<OB, B, 0, stream>>>(rowp, deg, esrc, row2, ad2, w2, b2,
                                    fw1, fb1, fw2, fb2, (float*)d_out, N);
}